// Round 12
// baseline (1138.104 us; speedup 1.0000x reference)
//
#include <hip/hip_runtime.h>
#include <math.h>

#define HD 256      // hidden dim
#define TPTS 32     // points per block (sampler chunk path)
#define KT 32       // k-tile for W2 staging (sampler chunk path)
#define SECNR 4     // rays per block (secant monolith) -- 4 verified best (r8/r10 A/B)
#define NSTEPS 100
#define TH 5e-5f

__device__ __forceinline__ float secant_pred(float sl, float sh, float zl, float zh) {
    float den = sh - sl;
    den = (fabsf(den) > 1e-12f) ? den : 1e-12f;
    return -sl * (zh - zl) / den + zl;
}

// ---------------------------------------------------------------------------
// Sampler CHUNK eval: list of rays, samples [sbase, sbase+slen) (+ sample 99
// if plus99). 32 points/block, 2-col threads, W2 staged through LDS.
// Verified at ~100% of fp32 VALU roofline.
// ---------------------------------------------------------------------------
__global__ __launch_bounds__(256, 2) void eval_chunk(
    const float* __restrict__ cam, const float* __restrict__ rays, int R,
    const int* __restrict__ list, const int* __restrict__ cnt,
    int sbase, int slen, int plus99,
    const float* __restrict__ smin, const float* __restrict__ smax,
    float* __restrict__ out,
    const float* __restrict__ W1, const float* __restrict__ b1,
    const float* __restrict__ W2, const float* __restrict__ b2,
    const float* __restrict__ W3, const float* __restrict__ b3)
{
    __shared__ float h1[TPTS][HD];     // 32 KB
    __shared__ float w2t[KT][HD];      // 32 KB
    __shared__ float ptsS[TPTS][4];
    __shared__ int   pidS[TPTS];
    __shared__ float redw[4][TPTS / 2];

    const int tid = threadIdx.x;
    const int v0  = blockIdx.x * TPTS;
    const int n   = cnt[0];
    const int CH  = slen + plus99;
    const int tot = n * CH;
    if (v0 >= tot) return;   // block-uniform early exit

    if (tid < TPTS) {
        int v = v0 + tid;
        int pid = -1;
        float px = 0.f, py = 0.f, pz = 0.f;
        if (v < tot) {
            int li = v / CH;
            int u  = v - li * CH;
            int st = (plus99 && u == slen) ? (NSTEPS - 1) : (sbase + u);
            int r = list[li];
            float a = smin[r], b = smax[r];
            float t = a + (b - a) * ((float)st / (float)(NSTEPS - 1));
            pid = r * NSTEPS + st;
            px = cam[3 * r + 0] + t * rays[3 * r + 0];
            py = cam[3 * r + 1] + t * rays[3 * r + 1];
            pz = cam[3 * r + 2] + t * rays[3 * r + 2];
        }
        ptsS[tid][0] = px; ptsS[tid][1] = py; ptsS[tid][2] = pz;
        pidS[tid] = pid;
    }
    __syncthreads();

    const int half  = tid >> 7;
    const int j0    = tid & 127;
    const int j1    = j0 + 128;
    const int pbase = half * (TPTS / 2);

    {
        float wa0 = W1[j0], wa1 = W1[HD + j0], wa2 = W1[2 * HD + j0], ba = b1[j0];
        float wb0 = W1[j1], wb1 = W1[HD + j1], wb2 = W1[2 * HD + j1], bb = b1[j1];
#pragma unroll
        for (int i = 0; i < TPTS / 2; ++i) {
            int p = pbase + i;
            float x = ptsS[p][0], y = ptsS[p][1], z = ptsS[p][2];
            h1[p][j0] = tanhf(ba + x * wa0 + y * wa1 + z * wa2);
            h1[p][j1] = tanhf(bb + x * wb0 + y * wb1 + z * wb2);
        }
    }
    __syncthreads();

    float acca[TPTS / 2], accb[TPTS / 2];
    {
        float b2a = b2[j0], b2b = b2[j1];
#pragma unroll
        for (int i = 0; i < TPTS / 2; ++i) { acca[i] = b2a; accb[i] = b2b; }
    }
    for (int k0 = 0; k0 < HD; k0 += KT) {
        for (int idx = tid; idx < KT * HD; idx += 256)
            ((float*)w2t)[idx] = W2[k0 * HD + idx];
        __syncthreads();
#pragma unroll
        for (int kk = 0; kk < KT; kk += 4) {
            float wa0 = w2t[kk][j0], wa1 = w2t[kk + 1][j0], wa2 = w2t[kk + 2][j0], wa3 = w2t[kk + 3][j0];
            float wb0 = w2t[kk][j1], wb1 = w2t[kk + 1][j1], wb2 = w2t[kk + 2][j1], wb3 = w2t[kk + 3][j1];
#pragma unroll
            for (int i = 0; i < TPTS / 2; ++i) {
                const float4 h4 = *(const float4*)&h1[pbase + i][k0 + kk];
                acca[i] = fmaf(h4.w, wa3, fmaf(h4.z, wa2, fmaf(h4.y, wa1, fmaf(h4.x, wa0, acca[i]))));
                accb[i] = fmaf(h4.w, wb3, fmaf(h4.z, wb2, fmaf(h4.y, wb1, fmaf(h4.x, wb0, accb[i]))));
            }
        }
        __syncthreads();
    }

    {
        float w3a = W3[j0], w3b = W3[j1];
        float sum[TPTS / 2];
#pragma unroll
        for (int i = 0; i < TPTS / 2; ++i)
            sum[i] = tanhf(acca[i]) * w3a + tanhf(accb[i]) * w3b;
#pragma unroll
        for (int off = 32; off > 0; off >>= 1)
#pragma unroll
            for (int i = 0; i < TPTS / 2; ++i)
                sum[i] += __shfl_down(sum[i], off);
        int wave = tid >> 6, lane = tid & 63;
        if (lane == 0)
#pragma unroll
            for (int i = 0; i < TPTS / 2; ++i) redw[wave][i] = sum[i];
    }
    __syncthreads();
    if (tid < TPTS) {
        int pid = pidS[tid];
        if (pid >= 0) {
            int p = tid;
            int w0 = (p < TPTS / 2) ? 0 : 2;
            int ii = p & (TPTS / 2 - 1);
            float tot3 = redw[w0][ii] + redw[w0 + 1][ii];
            float x = ptsS[p][0], y = ptsS[p][1], z = ptsS[p][2];
            float base = sqrtf(x * x + y * y + z * z + 1e-12f) - 0.6f;
            out[pid] = base + 0.05f * (tot3 + b3[0]);
        }
    }
}

// ---------------------------------------------------------------------------
// Trace iteration (round-8 structure): block owns 4 rays (8 endpoints).
// Prologue = fused k_step (mode 0: first eval, no step; 1: step dom=0;
// 2: step dom=1). Dense 1-col eval (unroll 8 for deep MLP). Epilogue writes
// nsdf for active endpoints + line-search update + listB append.
// ---------------------------------------------------------------------------
__global__ __launch_bounds__(256, 4) void k_iterA(
    const float* __restrict__ cam, const float* __restrict__ rays, int R,
    float* __restrict__ acc, float* __restrict__ nsdf, float* __restrict__ csdf,
    int* __restrict__ unfin, int mode,
    int doLS, int* __restrict__ listB, int* __restrict__ cntB,
    const float* __restrict__ W1, const float* __restrict__ b1,
    const float* __restrict__ W2, const float* __restrict__ b2,
    const float* __restrict__ W3, const float* __restrict__ b3)
{
    __shared__ float h1s[8][HD];       // 8 KB
    __shared__ float pS[8][4];
    __shared__ float accS[8], csdfS[8];
    __shared__ int   actS[8], pidS[8];
    __shared__ float red[4][8];

    const int tid = threadIdx.x;
    const int rbase = blockIdx.x * 4;

    // ---- prologue: fused per-ray step (exact k_step math) ----
    if (tid < 4) {
        int q = tid, r = rbase + q;
        if (r < R) {
            float as = acc[r], ae = acc[R + r];
            int us = unfin[r], ue = unfin[R + r];
            float cs = 0.f, ce = 0.f;
            if (mode >= 1) {
                if (mode == 2) { int d = as < ae; us = us && d; ue = ue && d; }
                cs = us ? nsdf[r] : 0.0f;     cs = (cs <= TH) ? 0.0f : cs;
                ce = ue ? nsdf[R + r] : 0.0f; ce = (ce <= TH) ? 0.0f : ce;
                us = us && (cs > TH); ue = ue && (ce > TH);
                as += cs; ae -= ce;
                acc[r] = as; acc[R + r] = ae;
                csdf[r] = cs; csdf[R + r] = ce;
                unfin[r] = us; unfin[R + r] = ue;
            }
            accS[q] = as; accS[4 + q] = ae;
            csdfS[q] = cs; csdfS[4 + q] = ce;
            actS[q] = us; actS[4 + q] = ue;
            pidS[q] = r; pidS[4 + q] = R + r;
        } else {
            accS[q] = 0.f; accS[4 + q] = 0.f;
            csdfS[q] = 0.f; csdfS[4 + q] = 0.f;
            actS[q] = 0; actS[4 + q] = 0;
            pidS[q] = -1; pidS[4 + q] = -1;
        }
    }
    __syncthreads();
    int na = __syncthreads_count(tid < 8 && actS[tid]);
    if (na == 0) return;     // state written; nothing to evaluate

    if (tid < 8) {
        int q = tid & 3;
        int r = rbase + q;
        float px = 0.f, py = 0.f, pz = 0.f;
        if (pidS[tid] >= 0) {
            float t = accS[tid];
            px = cam[3 * r + 0] + t * rays[3 * r + 0];
            py = cam[3 * r + 1] + t * rays[3 * r + 1];
            pz = cam[3 * r + 2] + t * rays[3 * r + 2];
        }
        pS[tid][0] = px; pS[tid][1] = py; pS[tid][2] = pz;
    }
    __syncthreads();

    // ---- dense 1-col eval of 8 endpoints ----
    const int j = tid;
    {
        float w0 = W1[j], w1 = W1[HD + j], w2 = W1[2 * HD + j], bb = b1[j];
#pragma unroll
        for (int p = 0; p < 8; ++p) {
            float x = pS[p][0], y = pS[p][1], z = pS[p][2];
            h1s[p][j] = tanhf(bb + x * w0 + y * w1 + z * w2);
        }
    }
    __syncthreads();

    float accv[8];
    {
        float b = b2[j];
#pragma unroll
        for (int p = 0; p < 8; ++p) accv[p] = b;
    }
#pragma unroll 8
    for (int k0 = 0; k0 < HD; k0 += 4) {
        float w0 = W2[(k0 + 0) * HD + j];
        float w1 = W2[(k0 + 1) * HD + j];
        float w2 = W2[(k0 + 2) * HD + j];
        float w3 = W2[(k0 + 3) * HD + j];
#pragma unroll
        for (int p = 0; p < 8; ++p) {
            const float4 h4 = *(const float4*)&h1s[p][k0];
            accv[p] = fmaf(h4.w, w3, fmaf(h4.z, w2, fmaf(h4.y, w1, fmaf(h4.x, w0, accv[p]))));
        }
    }

    {
        float w3c = W3[j];
        float sum[8];
#pragma unroll
        for (int p = 0; p < 8; ++p)
            sum[p] = tanhf(accv[p]) * w3c;
#pragma unroll
        for (int off = 32; off > 0; off >>= 1)
#pragma unroll
            for (int p = 0; p < 8; ++p)
                sum[p] += __shfl_down(sum[p], off);
        int wave = tid >> 6, lane = tid & 63;
        if (lane == 0)
#pragma unroll
            for (int p = 0; p < 8; ++p) red[wave][p] = sum[p];
    }
    __syncthreads();

    // ---- epilogue: nsdf write (active only) + line-search update ----
    if (tid < 8 && actS[tid]) {
        int pid = pidS[tid];
        float tot3 = red[0][tid] + red[1][tid] + red[2][tid] + red[3][tid];
        float x = pS[tid][0], y = pS[tid][1], z = pS[tid][2];
        float base = sqrtf(x * x + y * y + z * z + 1e-12f) - 0.6f;
        float s = base + 0.05f * (tot3 + b3[0]);
        nsdf[pid] = s;
        if (doLS && s < 0.0f) {
            float sgn = (tid < 4) ? -0.5f : 0.5f;   // step=(1-0.5)/2^0=0.5
            acc[pid] += sgn * csdfS[tid];
            int ix = atomicAdd(cntB, 1);
            listB[ix] = pid;
        }
    }
}

// ---------------------------------------------------------------------------
// SMALL path (line-search B-evals over compacted listB): 8 points/block,
// 1-col threads, W2 from global, unroll 8.
// ---------------------------------------------------------------------------
__global__ __launch_bounds__(256, 4) void eval_small(
    const float* __restrict__ cam, const float* __restrict__ rays, int R,
    const int* __restrict__ list, const int* __restrict__ cnt,
    const float* __restrict__ tarr,
    float* __restrict__ out,
    const float* __restrict__ W1, const float* __restrict__ b1,
    const float* __restrict__ W2, const float* __restrict__ b2,
    const float* __restrict__ W3, const float* __restrict__ b3)
{
    __shared__ float h1s[8][HD];
    __shared__ float pS[8][4];
    __shared__ int   pidS[8];
    __shared__ float red[4][8];

    const int tid = threadIdx.x;
    const int v0  = blockIdx.x * 8;
    const int n   = cnt[0];
    if (v0 >= n) return;

    if (tid < 8) {
        int v = v0 + tid;
        int pid = -1;
        float px = 0.f, py = 0.f, pz = 0.f;
        if (v < n) {
            int p = list[v];
            int r = (p < R) ? p : p - R;
            float t = tarr[p];
            pid = p;
            px = cam[3 * r + 0] + t * rays[3 * r + 0];
            py = cam[3 * r + 1] + t * rays[3 * r + 1];
            pz = cam[3 * r + 2] + t * rays[3 * r + 2];
        }
        pS[tid][0] = px; pS[tid][1] = py; pS[tid][2] = pz;
        pidS[tid] = pid;
    }
    __syncthreads();

    const int j = tid;
    {
        float w0 = W1[j], w1 = W1[HD + j], w2 = W1[2 * HD + j], bb = b1[j];
#pragma unroll
        for (int p = 0; p < 8; ++p) {
            float x = pS[p][0], y = pS[p][1], z = pS[p][2];
            h1s[p][j] = tanhf(bb + x * w0 + y * w1 + z * w2);
        }
    }
    __syncthreads();

    float acc[8];
    {
        float b = b2[j];
#pragma unroll
        for (int p = 0; p < 8; ++p) acc[p] = b;
    }
#pragma unroll 8
    for (int k0 = 0; k0 < HD; k0 += 4) {
        float w0 = W2[(k0 + 0) * HD + j];
        float w1 = W2[(k0 + 1) * HD + j];
        float w2 = W2[(k0 + 2) * HD + j];
        float w3 = W2[(k0 + 3) * HD + j];
#pragma unroll
        for (int p = 0; p < 8; ++p) {
            const float4 h4 = *(const float4*)&h1s[p][k0];
            acc[p] = fmaf(h4.w, w3, fmaf(h4.z, w2, fmaf(h4.y, w1, fmaf(h4.x, w0, acc[p]))));
        }
    }

    {
        float w3c = W3[j];
        float sum[8];
#pragma unroll
        for (int p = 0; p < 8; ++p)
            sum[p] = tanhf(acc[p]) * w3c;
#pragma unroll
        for (int off = 32; off > 0; off >>= 1)
#pragma unroll
            for (int p = 0; p < 8; ++p)
                sum[p] += __shfl_down(sum[p], off);
        int wave = tid >> 6, lane = tid & 63;
        if (lane == 0)
#pragma unroll
            for (int p = 0; p < 8; ++p) red[wave][p] = sum[p];
    }
    __syncthreads();

    if (tid < 8) {
        int pid = pidS[tid];
        if (pid >= 0) {
            float tot3 = red[0][tid] + red[1][tid] + red[2][tid] + red[3][tid];
            float x = pS[tid][0], y = pS[tid][1], z = pS[tid][2];
            float base = sqrtf(x * x + y * y + z * z + 1e-12f) - 0.6f;
            out[pid] = base + 0.05f * (tot3 + b3[0]);
        }
    }
}

// ---------------------------------------------------------------------------
__global__ void k_scan(const float* __restrict__ sdfv,
                       const int* __restrict__ listIn, const int* __restrict__ cntIn,
                       int sbase, int slen, int finalNE,
                       int* __restrict__ listOut, int* __restrict__ cntOut,
                       int* __restrict__ nEval)
{
    int jj = blockIdx.x * blockDim.x + threadIdx.x;
    if (jj >= cntIn[0]) return;
    int r = listIn[jj];
    int neg = 0;
    for (int i = 0; i < slen; ++i)
        neg |= (sdfv[r * NSTEPS + sbase + i] < 0.0f);
    if (neg) {
        nEval[r] = sbase + slen;
    } else {
        if (finalNE) nEval[r] = finalNE;
        int ix = atomicAdd(cntOut, 1);
        listOut[ix] = r;
    }
}

// ---------------------------------------------------------------------------
// MONOLITHIC secant: block owns 4 listS rays (verified best blocks-in-flight);
// argmin (bounded by nEval) + 8 secant iterations with exact fixed-point
// early exit + final writes. Dense inner loops, unroll 8.
// ---------------------------------------------------------------------------
__global__ __launch_bounds__(256, 2) void k_secfin(
    const float* __restrict__ cam, const float* __restrict__ rays, int R,
    const int* __restrict__ listS, const int* __restrict__ cntS,
    const float* __restrict__ sdfv, const int* __restrict__ nEval,
    const float* __restrict__ smin, const float* __restrict__ smax,
    float* __restrict__ out,
    const float* __restrict__ W1, const float* __restrict__ b1,
    const float* __restrict__ W2, const float* __restrict__ b2,
    const float* __restrict__ W3, const float* __restrict__ b3)
{
    __shared__ float h1s[SECNR][HD];
    __shared__ float pS[SECNR][4];
    __shared__ float camS[SECNR][3], raysS[SECNR][3];
    __shared__ float zlS[SECNR], zhS[SECNR], slS[SECNR], shS[SECNR], zpS[SECNR], sdoS[SECNR];
    __shared__ int   rS[SECNR], nsS[SECNR];
    __shared__ float red[4][SECNR];

    const int tid = threadIdx.x;
    const int n = cntS[0];
    const int jbase = blockIdx.x * SECNR;
    if (jbase >= n) return;
    const int j = tid;

    if (tid < SECNR) {
        int jj = jbase + tid;
        rS[tid] = (jj < n) ? listS[jj] : -1;
    }
    __syncthreads();
    if (tid < SECNR * 3) {
        int q = tid / 3, c = tid % 3;
        int r = rS[q];
        float cv = 0.f, rv = 0.f;
        if (r >= 0) { cv = cam[3 * r + c]; rv = rays[3 * r + c]; }
        camS[q][c] = cv; raysS[q][c] = rv;
    }
    if (tid < SECNR) {
        zpS[tid] = 0.f;
        pS[tid][0] = 0.f; pS[tid][1] = 0.f; pS[tid][2] = 0.f;
    }
    __syncthreads();

    // ---- argmin over evaluated prefix (exact first-negative semantics) ----
    if (tid < SECNR) {
        int r = rS[tid];
        if (r >= 0) {
            float a = smin[r], b = smax[r];
            float d = b - a;
            int ne = nEval[r];
            float best = 1e30f; int ind = 0;
            for (int i = 0; i < ne; ++i) {
                float sv = sdfv[r * NSTEPS + i];
                float sgn = (float)((sv > 0.0f) - (sv < 0.0f));
                float tmp = sgn * (float)(NSTEPS - i);
                if (tmp < best) { best = tmp; ind = i; }
            }
            float zh = a + d * ((float)ind / (float)(NSTEPS - 1));
            float sh = sdfv[r * NSTEPS + ind];
            int il = (ind + NSTEPS - 1) % NSTEPS;
            float zl = a + d * ((float)il / (float)(NSTEPS - 1));
            float sl = sdfv[r * NSTEPS + il];
            nsS[tid] = (sh < 0.0f);
            sdoS[tid] = zh;
            zlS[tid] = zl; zhS[tid] = zh; slS[tid] = sl; shS[tid] = sh;
            zpS[tid] = secant_pred(sl, sh, zl, zh);
        }
    }

    for (int si = 0; si < 8; ++si) {
        __syncthreads();
        if (tid < SECNR && rS[tid] >= 0) {
            float t = zpS[tid];
            pS[tid][0] = camS[tid][0] + t * raysS[tid][0];
            pS[tid][1] = camS[tid][1] + t * raysS[tid][1];
            pS[tid][2] = camS[tid][2] + t * raysS[tid][2];
        }
        __syncthreads();
        {
            float w0 = W1[j], w1 = W1[HD + j], w2 = W1[2 * HD + j], bb = b1[j];
#pragma unroll
            for (int e = 0; e < SECNR; ++e) {
                float x = pS[e][0], y = pS[e][1], z = pS[e][2];
                h1s[e][j] = tanhf(bb + x * w0 + y * w1 + z * w2);
            }
        }
        __syncthreads();
        float acc[SECNR];
        {
            float b = b2[j];
#pragma unroll
            for (int e = 0; e < SECNR; ++e) acc[e] = b;
        }
#pragma unroll 8
        for (int k0 = 0; k0 < HD; k0 += 4) {
            float u0 = W2[(k0 + 0) * HD + j];
            float u1 = W2[(k0 + 1) * HD + j];
            float u2 = W2[(k0 + 2) * HD + j];
            float u3 = W2[(k0 + 3) * HD + j];
#pragma unroll
            for (int e = 0; e < SECNR; ++e) {
                const float4 h4 = *(const float4*)&h1s[e][k0];
                acc[e] = fmaf(h4.w, u3, fmaf(h4.z, u2, fmaf(h4.y, u1, fmaf(h4.x, u0, acc[e]))));
            }
        }
        {
            float w3c = W3[j];
            float sum[SECNR];
#pragma unroll
            for (int e = 0; e < SECNR; ++e)
                sum[e] = tanhf(acc[e]) * w3c;
#pragma unroll
            for (int off = 32; off > 0; off >>= 1)
#pragma unroll
                for (int e = 0; e < SECNR; ++e)
                    sum[e] += __shfl_down(sum[e], off);
            int wave = tid >> 6, lane = tid & 63;
            if (lane == 0)
#pragma unroll
                for (int e = 0; e < SECNR; ++e) red[wave][e] = sum[e];
        }
        __syncthreads();
        int mych = 0;
        if (tid < SECNR && rS[tid] >= 0) {
            float tot3 = red[0][tid] + red[1][tid] + red[2][tid] + red[3][tid];
            float x = pS[tid][0], y = pS[tid][1], z = pS[tid][2];
            float base = sqrtf(x * x + y * y + z * z + 1e-12f) - 0.6f;
            float s = base + 0.05f * (tot3 + b3[0]);
            float zl = zlS[tid], zh = zhS[tid], sl = slS[tid], sh = shS[tid], zp = zpS[tid];
            float ozl = zl, ozh = zh, osl = sl, osh = sh, ozp = zp;
            if (s > 0.0f) { zl = zp; sl = s; }
            if (s < 0.0f) { zh = zp; sh = s; }
            zp = secant_pred(sl, sh, zl, zh);
            zlS[tid] = zl; zhS[tid] = zh; slS[tid] = sl; shS[tid] = sh; zpS[tid] = zp;
            mych = (zl != ozl) || (zh != ozh) || (sl != osl) || (sh != osh) || (zp != ozp);
        }
        int totch = __syncthreads_count(mych);
        if (totch == 0) break;   // exact fixed point: later iterations identical
    }

    __syncthreads();
    if (tid < SECNR) {
        int r = rS[tid];
        if (r >= 0) {
            int ns = nsS[tid];
            float dist = ns ? zpS[tid] : sdoS[tid];
            out[3 * r + 0] = camS[tid][0] + dist * raysS[tid][0];
            out[3 * r + 1] = camS[tid][1] + dist * raysS[tid][1];
            out[3 * r + 2] = camS[tid][2] + dist * raysS[tid][2];
            out[3 * R + r] = ns ? 1.0f : 0.0f;
            out[4 * R + r] = dist;
        }
    }
}

// ---------------------------------------------------------------------------
__global__ void k_zero(int* __restrict__ c) {
    if (threadIdx.x < 32) c[threadIdx.x] = 0;
}

__global__ void k_init(const float* __restrict__ cam, const float* __restrict__ rays,
                       float* __restrict__ acc, int* __restrict__ unfin, int R)
{
    int r = blockIdx.x * blockDim.x + threadIdx.x;
    if (r >= R) return;
    float cx = cam[3 * r], cy = cam[3 * r + 1], cz = cam[3 * r + 2];
    float dx = rays[3 * r], dy = rays[3 * r + 1], dz = rays[3 * r + 2];
    float rcd = cx * dx + cy * dy + cz * dz;
    float cc = cx * cx + cy * cy + cz * cz;
    float under = rcd * rcd - (cc - 1.0f);
    int mi = under > 0.0f;
    float sq = sqrtf(mi ? under : 1.0f);
    float a0 = mi ? fmaxf(-sq - rcd, 0.0f) : 0.0f;
    float a1 = mi ? fmaxf(sq - rcd, 0.0f) : 0.0f;
    acc[r] = a0; acc[R + r] = a1;
    unfin[r] = mi; unfin[R + r] = mi;
}

__global__ void k_post(const float* __restrict__ cam, const float* __restrict__ rays,
                       const float* __restrict__ acc, const float* __restrict__ nsdf,
                       const int* __restrict__ unfin,
                       int* __restrict__ listS, int* __restrict__ cntS,
                       float* __restrict__ smin, float* __restrict__ smax,
                       float* __restrict__ out, int R)
{
    int r = blockIdx.x * blockDim.x + threadIdx.x;
    if (r >= R) return;
    float as = acc[r], ae = acc[R + r];
    int us = unfin[r];
    int d = as < ae;
    us = us && d;                               // loop-end domain check
    float cs = us ? nsdf[r] : 0.0f;
    cs = (cs <= TH) ? 0.0f : cs;
    us = us && (cs > TH);                       // final mask refinement
    smin[r] = as;
    smax[r] = ae;
    if (us) listS[atomicAdd(cntS, 1)] = r;
    out[3 * r + 0] = cam[3 * r + 0] + as * rays[3 * r + 0];
    out[3 * r + 1] = cam[3 * r + 1] + as * rays[3 * r + 1];
    out[3 * r + 2] = cam[3 * r + 2] + as * rays[3 * r + 2];
    out[3 * R + r] = d ? 1.0f : 0.0f;
    out[4 * R + r] = as;
}

// ---------------------------------------------------------------------------
extern "C" void kernel_launch(void* const* d_in, const int* in_sizes, int n_in,
                              void* d_out, int out_size, void* d_ws, size_t ws_size,
                              hipStream_t stream)
{
    const float* cam  = (const float*)d_in[0];
    const float* rays = (const float*)d_in[1];
    const float* W1   = (const float*)d_in[3];
    const float* b1   = (const float*)d_in[4];
    const float* W2   = (const float*)d_in[5];
    const float* b2   = (const float*)d_in[6];
    const float* W3   = (const float*)d_in[7];
    const float* b3   = (const float*)d_in[8];
    const int R = in_sizes[0] / 3;
    float* out = (float*)d_out;

    float* f = (float*)d_ws;
    float* acc    = f; f += 2 * R;
    float* nsdf   = f; f += 2 * R;
    float* csdf   = f; f += 2 * R;
    float* smin   = f; f += R;
    float* smax   = f; f += R;
    float* sdfv   = f; f += R * NSTEPS;
    int* unfin    = (int*)f; f += 2 * R;
    int* listB    = (int*)f; f += 2 * R;
    int* listS    = (int*)f; f += R;
    int* listC1   = (int*)f; f += R;
    int* listC2   = (int*)f; f += R;
    int* listC3   = (int*)f; f += R;
    int* nEval    = (int*)f; f += R;
    int* cnt      = (int*)f; f += 32;
    // counter slots: 1..10 = listB per iter; 21 = listS; 22/23/24 = listC1/2/3

    const int gR   = (R + 255) / 256;                      // 16
    const int gA   = (R + 3) / 4;                          // 1024 (trace iters)
    const int gB   = (2 * R + 7) / 8;                      // 1024 (B-evals, early-exit)
    const int gC   = (R * 26 + TPTS - 1) / TPTS;           // 3328 (chunk evals, early-exit)
    const int gSec = (R + SECNR - 1) / SECNR;              // 1024 (secant)

    auto iterA = [&](int mode, int doLS, int* cB) {
        hipLaunchKernelGGL(k_iterA, dim3(gA), dim3(256), 0, stream,
                           cam, rays, R, acc, nsdf, csdf, unfin, mode,
                           doLS, listB, cB, W1, b1, W2, b2, W3, b3);
    };
    auto chunk = [&](const int* lst, const int* c, int sbase, int slen, int plus99) {
        hipLaunchKernelGGL(eval_chunk, dim3(gC), dim3(256), 0, stream,
                           cam, rays, R, lst, c, sbase, slen, plus99,
                           smin, smax, sdfv, W1, b1, W2, b2, W3, b3);
    };

    k_zero<<<1, 64, 0, stream>>>(cnt);
    k_init<<<gR, 256, 0, stream>>>(cam, rays, acc, unfin, R);
    iterA(0, 0, cnt + 31);                                 // first eval, no step/LS

    for (int it = 0; it < 10; ++it) {
        iterA(it == 0 ? 1 : 2, 1, cnt + 1 + it);           // fused step + eval + LS
        hipLaunchKernelGGL(eval_small, dim3(gB), dim3(256), 0, stream,
                           cam, rays, R, listB, cnt + 1 + it, acc, nsdf,
                           W1, b1, W2, b2, W3, b3);        // B-eval (np points)
    }

    k_post<<<gR, 256, 0, stream>>>(cam, rays, acc, nsdf, unfin, listS, cnt + 21,
                                   smin, smax, out, R);

    // chunked sampler with exact first-negative early exit
    chunk(listS, cnt + 21, 0, 25, 1);                      // samples 0..24 + 99
    k_scan<<<gR, 256, 0, stream>>>(sdfv, listS, cnt + 21, 0, 25, 0,
                                   listC1, cnt + 22, nEval);
    chunk(listC1, cnt + 22, 25, 25, 0);                    // samples 25..49
    k_scan<<<gR, 256, 0, stream>>>(sdfv, listC1, cnt + 22, 25, 25, 0,
                                   listC2, cnt + 23, nEval);
    chunk(listC2, cnt + 23, 50, 25, 0);                    // samples 50..74
    k_scan<<<gR, 256, 0, stream>>>(sdfv, listC2, cnt + 23, 50, 25, 100,
                                   listC3, cnt + 24, nEval);
    chunk(listC3, cnt + 24, 75, 24, 0);                    // samples 75..98

    hipLaunchKernelGGL(k_secfin, dim3(gSec), dim3(256), 0, stream,
                       cam, rays, R, listS, cnt + 21, sdfv, nEval, smin, smax, out,
                       W1, b1, W2, b2, W3, b3);
}

// Round 13
// 824.864 us; speedup vs baseline: 1.3797x; 1.3797x over previous
//
#include <hip/hip_runtime.h>
#include <math.h>

#define HD 256      // hidden dim
#define TPTS 32     // points per block (sampler chunk path)
#define KT 32       // k-tile for W2 staging (sampler chunk path)
#define SECNR 4     // rays per block (secant monolith) -- 4 verified best
#define NSTEPS 100
#define TH 5e-5f

__device__ __forceinline__ float secant_pred(float sl, float sh, float zl, float zh) {
    float den = sh - sl;
    den = (fabsf(den) > 1e-12f) ? den : 1e-12f;
    return -sl * (zh - zl) / den + zl;
}

// ---------------------------------------------------------------------------
// Sampler CHUNK eval: list of rays, samples [sbase, sbase+slen) (+ sample 99
// if plus99). 32 points/block, 2-col threads, W2 staged through LDS.
// Verified at ~100% of fp32 VALU roofline.
// ---------------------------------------------------------------------------
__global__ __launch_bounds__(256, 2) void eval_chunk(
    const float* __restrict__ cam, const float* __restrict__ rays, int R,
    const int* __restrict__ list, const int* __restrict__ cnt,
    int sbase, int slen, int plus99,
    const float* __restrict__ smin, const float* __restrict__ smax,
    float* __restrict__ out,
    const float* __restrict__ W1, const float* __restrict__ b1,
    const float* __restrict__ W2, const float* __restrict__ b2,
    const float* __restrict__ W3, const float* __restrict__ b3)
{
    __shared__ float h1[TPTS][HD];     // 32 KB
    __shared__ float w2t[KT][HD];      // 32 KB
    __shared__ float ptsS[TPTS][4];
    __shared__ int   pidS[TPTS];
    __shared__ float redw[4][TPTS / 2];

    const int tid = threadIdx.x;
    const int v0  = blockIdx.x * TPTS;
    const int n   = cnt[0];
    const int CH  = slen + plus99;
    const int tot = n * CH;
    if (v0 >= tot) return;   // block-uniform early exit

    if (tid < TPTS) {
        int v = v0 + tid;
        int pid = -1;
        float px = 0.f, py = 0.f, pz = 0.f;
        if (v < tot) {
            int li = v / CH;
            int u  = v - li * CH;
            int st = (plus99 && u == slen) ? (NSTEPS - 1) : (sbase + u);
            int r = list[li];
            float a = smin[r], b = smax[r];
            float t = a + (b - a) * ((float)st / (float)(NSTEPS - 1));
            pid = r * NSTEPS + st;
            px = cam[3 * r + 0] + t * rays[3 * r + 0];
            py = cam[3 * r + 1] + t * rays[3 * r + 1];
            pz = cam[3 * r + 2] + t * rays[3 * r + 2];
        }
        ptsS[tid][0] = px; ptsS[tid][1] = py; ptsS[tid][2] = pz;
        pidS[tid] = pid;
    }
    __syncthreads();

    const int half  = tid >> 7;
    const int j0    = tid & 127;
    const int j1    = j0 + 128;
    const int pbase = half * (TPTS / 2);

    {
        float wa0 = W1[j0], wa1 = W1[HD + j0], wa2 = W1[2 * HD + j0], ba = b1[j0];
        float wb0 = W1[j1], wb1 = W1[HD + j1], wb2 = W1[2 * HD + j1], bb = b1[j1];
#pragma unroll
        for (int i = 0; i < TPTS / 2; ++i) {
            int p = pbase + i;
            float x = ptsS[p][0], y = ptsS[p][1], z = ptsS[p][2];
            h1[p][j0] = tanhf(ba + x * wa0 + y * wa1 + z * wa2);
            h1[p][j1] = tanhf(bb + x * wb0 + y * wb1 + z * wb2);
        }
    }
    __syncthreads();

    float acca[TPTS / 2], accb[TPTS / 2];
    {
        float b2a = b2[j0], b2b = b2[j1];
#pragma unroll
        for (int i = 0; i < TPTS / 2; ++i) { acca[i] = b2a; accb[i] = b2b; }
    }
    for (int k0 = 0; k0 < HD; k0 += KT) {
        for (int idx = tid; idx < KT * HD; idx += 256)
            ((float*)w2t)[idx] = W2[k0 * HD + idx];
        __syncthreads();
#pragma unroll
        for (int kk = 0; kk < KT; kk += 4) {
            float wa0 = w2t[kk][j0], wa1 = w2t[kk + 1][j0], wa2 = w2t[kk + 2][j0], wa3 = w2t[kk + 3][j0];
            float wb0 = w2t[kk][j1], wb1 = w2t[kk + 1][j1], wb2 = w2t[kk + 2][j1], wb3 = w2t[kk + 3][j1];
#pragma unroll
            for (int i = 0; i < TPTS / 2; ++i) {
                const float4 h4 = *(const float4*)&h1[pbase + i][k0 + kk];
                acca[i] = fmaf(h4.w, wa3, fmaf(h4.z, wa2, fmaf(h4.y, wa1, fmaf(h4.x, wa0, acca[i]))));
                accb[i] = fmaf(h4.w, wb3, fmaf(h4.z, wb2, fmaf(h4.y, wb1, fmaf(h4.x, wb0, accb[i]))));
            }
        }
        __syncthreads();
    }

    {
        float w3a = W3[j0], w3b = W3[j1];
        float sum[TPTS / 2];
#pragma unroll
        for (int i = 0; i < TPTS / 2; ++i)
            sum[i] = tanhf(acca[i]) * w3a + tanhf(accb[i]) * w3b;
#pragma unroll
        for (int off = 32; off > 0; off >>= 1)
#pragma unroll
            for (int i = 0; i < TPTS / 2; ++i)
                sum[i] += __shfl_down(sum[i], off);
        int wave = tid >> 6, lane = tid & 63;
        if (lane == 0)
#pragma unroll
            for (int i = 0; i < TPTS / 2; ++i) redw[wave][i] = sum[i];
    }
    __syncthreads();
    if (tid < TPTS) {
        int pid = pidS[tid];
        if (pid >= 0) {
            int p = tid;
            int w0 = (p < TPTS / 2) ? 0 : 2;
            int ii = p & (TPTS / 2 - 1);
            float tot3 = redw[w0][ii] + redw[w0 + 1][ii];
            float x = ptsS[p][0], y = ptsS[p][1], z = ptsS[p][2];
            float base = sqrtf(x * x + y * y + z * z + 1e-12f) - 0.6f;
            out[pid] = base + 0.05f * (tot3 + b3[0]);
        }
    }
}

// ---------------------------------------------------------------------------
// Trace iteration (round-8 verified): block owns 4 rays (8 endpoints).
// Prologue = fused k_step (mode 0: first eval, no step; 1: step dom=0;
// 2: step dom=1). Dense 1-col eval (unroll 4 -- verified best). Epilogue
// writes nsdf for active endpoints + line-search update + listB append.
// ---------------------------------------------------------------------------
__global__ __launch_bounds__(256, 4) void k_iterA(
    const float* __restrict__ cam, const float* __restrict__ rays, int R,
    float* __restrict__ acc, float* __restrict__ nsdf, float* __restrict__ csdf,
    int* __restrict__ unfin, int mode,
    int doLS, int* __restrict__ listB, int* __restrict__ cntB,
    const float* __restrict__ W1, const float* __restrict__ b1,
    const float* __restrict__ W2, const float* __restrict__ b2,
    const float* __restrict__ W3, const float* __restrict__ b3)
{
    __shared__ float h1s[8][HD];       // 8 KB
    __shared__ float pS[8][4];
    __shared__ float accS[8], csdfS[8];
    __shared__ int   actS[8], pidS[8];
    __shared__ float red[4][8];

    const int tid = threadIdx.x;
    const int rbase = blockIdx.x * 4;

    // ---- prologue: fused per-ray step (exact k_step math) ----
    if (tid < 4) {
        int q = tid, r = rbase + q;
        if (r < R) {
            float as = acc[r], ae = acc[R + r];
            int us = unfin[r], ue = unfin[R + r];
            float cs = 0.f, ce = 0.f;
            if (mode >= 1) {
                if (mode == 2) { int d = as < ae; us = us && d; ue = ue && d; }
                cs = us ? nsdf[r] : 0.0f;     cs = (cs <= TH) ? 0.0f : cs;
                ce = ue ? nsdf[R + r] : 0.0f; ce = (ce <= TH) ? 0.0f : ce;
                us = us && (cs > TH); ue = ue && (ce > TH);
                as += cs; ae -= ce;
                acc[r] = as; acc[R + r] = ae;
                csdf[r] = cs; csdf[R + r] = ce;
                unfin[r] = us; unfin[R + r] = ue;
            }
            accS[q] = as; accS[4 + q] = ae;
            csdfS[q] = cs; csdfS[4 + q] = ce;
            actS[q] = us; actS[4 + q] = ue;
            pidS[q] = r; pidS[4 + q] = R + r;
        } else {
            accS[q] = 0.f; accS[4 + q] = 0.f;
            csdfS[q] = 0.f; csdfS[4 + q] = 0.f;
            actS[q] = 0; actS[4 + q] = 0;
            pidS[q] = -1; pidS[4 + q] = -1;
        }
    }
    __syncthreads();
    int na = __syncthreads_count(tid < 8 && actS[tid]);
    if (na == 0) return;     // state written; nothing to evaluate

    if (tid < 8) {
        int q = tid & 3;
        int r = rbase + q;
        float px = 0.f, py = 0.f, pz = 0.f;
        if (pidS[tid] >= 0) {
            float t = accS[tid];
            px = cam[3 * r + 0] + t * rays[3 * r + 0];
            py = cam[3 * r + 1] + t * rays[3 * r + 1];
            pz = cam[3 * r + 2] + t * rays[3 * r + 2];
        }
        pS[tid][0] = px; pS[tid][1] = py; pS[tid][2] = pz;
    }
    __syncthreads();

    // ---- dense 1-col eval of 8 endpoints ----
    const int j = tid;
    {
        float w0 = W1[j], w1 = W1[HD + j], w2 = W1[2 * HD + j], bb = b1[j];
#pragma unroll
        for (int p = 0; p < 8; ++p) {
            float x = pS[p][0], y = pS[p][1], z = pS[p][2];
            h1s[p][j] = tanhf(bb + x * w0 + y * w1 + z * w2);
        }
    }
    __syncthreads();

    float accv[8];
    {
        float b = b2[j];
#pragma unroll
        for (int p = 0; p < 8; ++p) accv[p] = b;
    }
#pragma unroll 4
    for (int k0 = 0; k0 < HD; k0 += 4) {
        float w0 = W2[(k0 + 0) * HD + j];
        float w1 = W2[(k0 + 1) * HD + j];
        float w2 = W2[(k0 + 2) * HD + j];
        float w3 = W2[(k0 + 3) * HD + j];
#pragma unroll
        for (int p = 0; p < 8; ++p) {
            const float4 h4 = *(const float4*)&h1s[p][k0];
            accv[p] = fmaf(h4.w, w3, fmaf(h4.z, w2, fmaf(h4.y, w1, fmaf(h4.x, w0, accv[p]))));
        }
    }

    {
        float w3c = W3[j];
        float sum[8];
#pragma unroll
        for (int p = 0; p < 8; ++p)
            sum[p] = tanhf(accv[p]) * w3c;
#pragma unroll
        for (int off = 32; off > 0; off >>= 1)
#pragma unroll
            for (int p = 0; p < 8; ++p)
                sum[p] += __shfl_down(sum[p], off);
        int wave = tid >> 6, lane = tid & 63;
        if (lane == 0)
#pragma unroll
            for (int p = 0; p < 8; ++p) red[wave][p] = sum[p];
    }
    __syncthreads();

    // ---- epilogue: nsdf write (active only) + line-search update ----
    if (tid < 8 && actS[tid]) {
        int pid = pidS[tid];
        float tot3 = red[0][tid] + red[1][tid] + red[2][tid] + red[3][tid];
        float x = pS[tid][0], y = pS[tid][1], z = pS[tid][2];
        float base = sqrtf(x * x + y * y + z * z + 1e-12f) - 0.6f;
        float s = base + 0.05f * (tot3 + b3[0]);
        nsdf[pid] = s;
        if (doLS && s < 0.0f) {
            float sgn = (tid < 4) ? -0.5f : 0.5f;   // step=(1-0.5)/2^0=0.5
            acc[pid] += sgn * csdfS[tid];
            int ix = atomicAdd(cntB, 1);
            listB[ix] = pid;
        }
    }
}

// ---------------------------------------------------------------------------
// SMALL path (line-search B-evals over compacted listB): 8 points/block,
// 1-col threads, W2 from global, unroll 4 (verified).
// ---------------------------------------------------------------------------
__global__ __launch_bounds__(256, 4) void eval_small(
    const float* __restrict__ cam, const float* __restrict__ rays, int R,
    const int* __restrict__ list, const int* __restrict__ cnt,
    const float* __restrict__ tarr,
    float* __restrict__ out,
    const float* __restrict__ W1, const float* __restrict__ b1,
    const float* __restrict__ W2, const float* __restrict__ b2,
    const float* __restrict__ W3, const float* __restrict__ b3)
{
    __shared__ float h1s[8][HD];
    __shared__ float pS[8][4];
    __shared__ int   pidS[8];
    __shared__ float red[4][8];

    const int tid = threadIdx.x;
    const int v0  = blockIdx.x * 8;
    const int n   = cnt[0];
    if (v0 >= n) return;

    if (tid < 8) {
        int v = v0 + tid;
        int pid = -1;
        float px = 0.f, py = 0.f, pz = 0.f;
        if (v < n) {
            int p = list[v];
            int r = (p < R) ? p : p - R;
            float t = tarr[p];
            pid = p;
            px = cam[3 * r + 0] + t * rays[3 * r + 0];
            py = cam[3 * r + 1] + t * rays[3 * r + 1];
            pz = cam[3 * r + 2] + t * rays[3 * r + 2];
        }
        pS[tid][0] = px; pS[tid][1] = py; pS[tid][2] = pz;
        pidS[tid] = pid;
    }
    __syncthreads();

    const int j = tid;
    {
        float w0 = W1[j], w1 = W1[HD + j], w2 = W1[2 * HD + j], bb = b1[j];
#pragma unroll
        for (int p = 0; p < 8; ++p) {
            float x = pS[p][0], y = pS[p][1], z = pS[p][2];
            h1s[p][j] = tanhf(bb + x * w0 + y * w1 + z * w2);
        }
    }
    __syncthreads();

    float acc[8];
    {
        float b = b2[j];
#pragma unroll
        for (int p = 0; p < 8; ++p) acc[p] = b;
    }
#pragma unroll 4
    for (int k0 = 0; k0 < HD; k0 += 4) {
        float w0 = W2[(k0 + 0) * HD + j];
        float w1 = W2[(k0 + 1) * HD + j];
        float w2 = W2[(k0 + 2) * HD + j];
        float w3 = W2[(k0 + 3) * HD + j];
#pragma unroll
        for (int p = 0; p < 8; ++p) {
            const float4 h4 = *(const float4*)&h1s[p][k0];
            acc[p] = fmaf(h4.w, w3, fmaf(h4.z, w2, fmaf(h4.y, w1, fmaf(h4.x, w0, acc[p]))));
        }
    }

    {
        float w3c = W3[j];
        float sum[8];
#pragma unroll
        for (int p = 0; p < 8; ++p)
            sum[p] = tanhf(acc[p]) * w3c;
#pragma unroll
        for (int off = 32; off > 0; off >>= 1)
#pragma unroll
            for (int p = 0; p < 8; ++p)
                sum[p] += __shfl_down(sum[p], off);
        int wave = tid >> 6, lane = tid & 63;
        if (lane == 0)
#pragma unroll
            for (int p = 0; p < 8; ++p) red[wave][p] = sum[p];
    }
    __syncthreads();

    if (tid < 8) {
        int pid = pidS[tid];
        if (pid >= 0) {
            float tot3 = red[0][tid] + red[1][tid] + red[2][tid] + red[3][tid];
            float x = pS[tid][0], y = pS[tid][1], z = pS[tid][2];
            float base = sqrtf(x * x + y * y + z * z + 1e-12f) - 0.6f;
            out[pid] = base + 0.05f * (tot3 + b3[0]);
        }
    }
}

// ---------------------------------------------------------------------------
__global__ void k_scan(const float* __restrict__ sdfv,
                       const int* __restrict__ listIn, const int* __restrict__ cntIn,
                       int sbase, int slen, int finalNE,
                       int* __restrict__ listOut, int* __restrict__ cntOut,
                       int* __restrict__ nEval)
{
    int jj = blockIdx.x * blockDim.x + threadIdx.x;
    if (jj >= cntIn[0]) return;
    int r = listIn[jj];
    int neg = 0;
    for (int i = 0; i < slen; ++i)
        neg |= (sdfv[r * NSTEPS + sbase + i] < 0.0f);
    if (neg) {
        nEval[r] = sbase + slen;
    } else {
        if (finalNE) nEval[r] = finalNE;
        int ix = atomicAdd(cntOut, 1);
        listOut[ix] = r;
    }
}

// ---------------------------------------------------------------------------
// MONOLITHIC secant: block owns 4 listS rays (verified best blocks-in-flight);
// argmin (bounded by nEval) + 8 secant iterations with exact fixed-point
// early exit (round-9 verified) + final writes. Unroll 4 (verified).
// ---------------------------------------------------------------------------
__global__ __launch_bounds__(256, 2) void k_secfin(
    const float* __restrict__ cam, const float* __restrict__ rays, int R,
    const int* __restrict__ listS, const int* __restrict__ cntS,
    const float* __restrict__ sdfv, const int* __restrict__ nEval,
    const float* __restrict__ smin, const float* __restrict__ smax,
    float* __restrict__ out,
    const float* __restrict__ W1, const float* __restrict__ b1,
    const float* __restrict__ W2, const float* __restrict__ b2,
    const float* __restrict__ W3, const float* __restrict__ b3)
{
    __shared__ float h1s[SECNR][HD];
    __shared__ float pS[SECNR][4];
    __shared__ float camS[SECNR][3], raysS[SECNR][3];
    __shared__ float zlS[SECNR], zhS[SECNR], slS[SECNR], shS[SECNR], zpS[SECNR], sdoS[SECNR];
    __shared__ int   rS[SECNR], nsS[SECNR];
    __shared__ float red[4][SECNR];

    const int tid = threadIdx.x;
    const int n = cntS[0];
    const int jbase = blockIdx.x * SECNR;
    if (jbase >= n) return;
    const int j = tid;

    if (tid < SECNR) {
        int jj = jbase + tid;
        rS[tid] = (jj < n) ? listS[jj] : -1;
    }
    __syncthreads();
    if (tid < SECNR * 3) {
        int q = tid / 3, c = tid % 3;
        int r = rS[q];
        float cv = 0.f, rv = 0.f;
        if (r >= 0) { cv = cam[3 * r + c]; rv = rays[3 * r + c]; }
        camS[q][c] = cv; raysS[q][c] = rv;
    }
    if (tid < SECNR) {
        zpS[tid] = 0.f;
        pS[tid][0] = 0.f; pS[tid][1] = 0.f; pS[tid][2] = 0.f;
    }
    __syncthreads();

    // ---- argmin over evaluated prefix (exact first-negative semantics) ----
    if (tid < SECNR) {
        int r = rS[tid];
        if (r >= 0) {
            float a = smin[r], b = smax[r];
            float d = b - a;
            int ne = nEval[r];
            float best = 1e30f; int ind = 0;
            for (int i = 0; i < ne; ++i) {
                float sv = sdfv[r * NSTEPS + i];
                float sgn = (float)((sv > 0.0f) - (sv < 0.0f));
                float tmp = sgn * (float)(NSTEPS - i);
                if (tmp < best) { best = tmp; ind = i; }
            }
            float zh = a + d * ((float)ind / (float)(NSTEPS - 1));
            float sh = sdfv[r * NSTEPS + ind];
            int il = (ind + NSTEPS - 1) % NSTEPS;
            float zl = a + d * ((float)il / (float)(NSTEPS - 1));
            float sl = sdfv[r * NSTEPS + il];
            nsS[tid] = (sh < 0.0f);
            sdoS[tid] = zh;
            zlS[tid] = zl; zhS[tid] = zh; slS[tid] = sl; shS[tid] = sh;
            zpS[tid] = secant_pred(sl, sh, zl, zh);
        }
    }

    for (int si = 0; si < 8; ++si) {
        __syncthreads();
        if (tid < SECNR && rS[tid] >= 0) {
            float t = zpS[tid];
            pS[tid][0] = camS[tid][0] + t * raysS[tid][0];
            pS[tid][1] = camS[tid][1] + t * raysS[tid][1];
            pS[tid][2] = camS[tid][2] + t * raysS[tid][2];
        }
        __syncthreads();
        {
            float w0 = W1[j], w1 = W1[HD + j], w2 = W1[2 * HD + j], bb = b1[j];
#pragma unroll
            for (int e = 0; e < SECNR; ++e) {
                float x = pS[e][0], y = pS[e][1], z = pS[e][2];
                h1s[e][j] = tanhf(bb + x * w0 + y * w1 + z * w2);
            }
        }
        __syncthreads();
        float acc[SECNR];
        {
            float b = b2[j];
#pragma unroll
            for (int e = 0; e < SECNR; ++e) acc[e] = b;
        }
#pragma unroll 4
        for (int k0 = 0; k0 < HD; k0 += 4) {
            float u0 = W2[(k0 + 0) * HD + j];
            float u1 = W2[(k0 + 1) * HD + j];
            float u2 = W2[(k0 + 2) * HD + j];
            float u3 = W2[(k0 + 3) * HD + j];
#pragma unroll
            for (int e = 0; e < SECNR; ++e) {
                const float4 h4 = *(const float4*)&h1s[e][k0];
                acc[e] = fmaf(h4.w, u3, fmaf(h4.z, u2, fmaf(h4.y, u1, fmaf(h4.x, u0, acc[e]))));
            }
        }
        {
            float w3c = W3[j];
            float sum[SECNR];
#pragma unroll
            for (int e = 0; e < SECNR; ++e)
                sum[e] = tanhf(acc[e]) * w3c;
#pragma unroll
            for (int off = 32; off > 0; off >>= 1)
#pragma unroll
                for (int e = 0; e < SECNR; ++e)
                    sum[e] += __shfl_down(sum[e], off);
            int wave = tid >> 6, lane = tid & 63;
            if (lane == 0)
#pragma unroll
                for (int e = 0; e < SECNR; ++e) red[wave][e] = sum[e];
        }
        __syncthreads();
        int mych = 0;
        if (tid < SECNR && rS[tid] >= 0) {
            float tot3 = red[0][tid] + red[1][tid] + red[2][tid] + red[3][tid];
            float x = pS[tid][0], y = pS[tid][1], z = pS[tid][2];
            float base = sqrtf(x * x + y * y + z * z + 1e-12f) - 0.6f;
            float s = base + 0.05f * (tot3 + b3[0]);
            float zl = zlS[tid], zh = zhS[tid], sl = slS[tid], sh = shS[tid], zp = zpS[tid];
            float ozl = zl, ozh = zh, osl = sl, osh = sh, ozp = zp;
            if (s > 0.0f) { zl = zp; sl = s; }
            if (s < 0.0f) { zh = zp; sh = s; }
            zp = secant_pred(sl, sh, zl, zh);
            zlS[tid] = zl; zhS[tid] = zh; slS[tid] = sl; shS[tid] = sh; zpS[tid] = zp;
            mych = (zl != ozl) || (zh != ozh) || (sl != osl) || (sh != osh) || (zp != ozp);
        }
        int totch = __syncthreads_count(mych);
        if (totch == 0) break;   // exact fixed point: later iterations identical
    }

    __syncthreads();
    if (tid < SECNR) {
        int r = rS[tid];
        if (r >= 0) {
            int ns = nsS[tid];
            float dist = ns ? zpS[tid] : sdoS[tid];
            out[3 * r + 0] = camS[tid][0] + dist * raysS[tid][0];
            out[3 * r + 1] = camS[tid][1] + dist * raysS[tid][1];
            out[3 * r + 2] = camS[tid][2] + dist * raysS[tid][2];
            out[3 * R + r] = ns ? 1.0f : 0.0f;
            out[4 * R + r] = dist;
        }
    }
}

// ---------------------------------------------------------------------------
__global__ void k_zero(int* __restrict__ c) {
    if (threadIdx.x < 32) c[threadIdx.x] = 0;
}

__global__ void k_init(const float* __restrict__ cam, const float* __restrict__ rays,
                       float* __restrict__ acc, int* __restrict__ unfin, int R)
{
    int r = blockIdx.x * blockDim.x + threadIdx.x;
    if (r >= R) return;
    float cx = cam[3 * r], cy = cam[3 * r + 1], cz = cam[3 * r + 2];
    float dx = rays[3 * r], dy = rays[3 * r + 1], dz = rays[3 * r + 2];
    float rcd = cx * dx + cy * dy + cz * dz;
    float cc = cx * cx + cy * cy + cz * cz;
    float under = rcd * rcd - (cc - 1.0f);
    int mi = under > 0.0f;
    float sq = sqrtf(mi ? under : 1.0f);
    float a0 = mi ? fmaxf(-sq - rcd, 0.0f) : 0.0f;
    float a1 = mi ? fmaxf(sq - rcd, 0.0f) : 0.0f;
    acc[r] = a0; acc[R + r] = a1;
    unfin[r] = mi; unfin[R + r] = mi;
}

__global__ void k_post(const float* __restrict__ cam, const float* __restrict__ rays,
                       const float* __restrict__ acc, const float* __restrict__ nsdf,
                       const int* __restrict__ unfin,
                       int* __restrict__ listS, int* __restrict__ cntS,
                       float* __restrict__ smin, float* __restrict__ smax,
                       float* __restrict__ out, int R)
{
    int r = blockIdx.x * blockDim.x + threadIdx.x;
    if (r >= R) return;
    float as = acc[r], ae = acc[R + r];
    int us = unfin[r];
    int d = as < ae;
    us = us && d;                               // loop-end domain check
    float cs = us ? nsdf[r] : 0.0f;
    cs = (cs <= TH) ? 0.0f : cs;
    us = us && (cs > TH);                       // final mask refinement
    smin[r] = as;
    smax[r] = ae;
    if (us) listS[atomicAdd(cntS, 1)] = r;
    out[3 * r + 0] = cam[3 * r + 0] + as * rays[3 * r + 0];
    out[3 * r + 1] = cam[3 * r + 1] + as * rays[3 * r + 1];
    out[3 * r + 2] = cam[3 * r + 2] + as * rays[3 * r + 2];
    out[3 * R + r] = d ? 1.0f : 0.0f;
    out[4 * R + r] = as;
}

// ---------------------------------------------------------------------------
extern "C" void kernel_launch(void* const* d_in, const int* in_sizes, int n_in,
                              void* d_out, int out_size, void* d_ws, size_t ws_size,
                              hipStream_t stream)
{
    const float* cam  = (const float*)d_in[0];
    const float* rays = (const float*)d_in[1];
    const float* W1   = (const float*)d_in[3];
    const float* b1   = (const float*)d_in[4];
    const float* W2   = (const float*)d_in[5];
    const float* b2   = (const float*)d_in[6];
    const float* W3   = (const float*)d_in[7];
    const float* b3   = (const float*)d_in[8];
    const int R = in_sizes[0] / 3;
    float* out = (float*)d_out;

    float* f = (float*)d_ws;
    float* acc    = f; f += 2 * R;
    float* nsdf   = f; f += 2 * R;
    float* csdf   = f; f += 2 * R;
    float* smin   = f; f += R;
    float* smax   = f; f += R;
    float* sdfv   = f; f += R * NSTEPS;
    int* unfin    = (int*)f; f += 2 * R;
    int* listB    = (int*)f; f += 2 * R;
    int* listS    = (int*)f; f += R;
    int* listC1   = (int*)f; f += R;
    int* listC2   = (int*)f; f += R;
    int* listC3   = (int*)f; f += R;
    int* nEval    = (int*)f; f += R;
    int* cnt      = (int*)f; f += 32;
    // counter slots: 1..10 = listB per iter; 21 = listS; 22/23/24 = listC1/2/3

    const int gR   = (R + 255) / 256;                      // 16
    const int gA   = (R + 3) / 4;                          // 1024 (trace iters)
    const int gB   = (2 * R + 7) / 8;                      // 1024 (B-evals, early-exit)
    const int gC   = (R * 26 + TPTS - 1) / TPTS;           // 3328 (chunk evals, early-exit)
    const int gSec = (R + SECNR - 1) / SECNR;              // 1024 (secant)

    auto iterA = [&](int mode, int doLS, int* cB) {
        hipLaunchKernelGGL(k_iterA, dim3(gA), dim3(256), 0, stream,
                           cam, rays, R, acc, nsdf, csdf, unfin, mode,
                           doLS, listB, cB, W1, b1, W2, b2, W3, b3);
    };
    auto chunk = [&](const int* lst, const int* c, int sbase, int slen, int plus99) {
        hipLaunchKernelGGL(eval_chunk, dim3(gC), dim3(256), 0, stream,
                           cam, rays, R, lst, c, sbase, slen, plus99,
                           smin, smax, sdfv, W1, b1, W2, b2, W3, b3);
    };

    k_zero<<<1, 64, 0, stream>>>(cnt);
    k_init<<<gR, 256, 0, stream>>>(cam, rays, acc, unfin, R);
    iterA(0, 0, cnt + 31);                                 // first eval, no step/LS

    for (int it = 0; it < 10; ++it) {
        iterA(it == 0 ? 1 : 2, 1, cnt + 1 + it);           // fused step + eval + LS
        hipLaunchKernelGGL(eval_small, dim3(gB), dim3(256), 0, stream,
                           cam, rays, R, listB, cnt + 1 + it, acc, nsdf,
                           W1, b1, W2, b2, W3, b3);        // B-eval (np points)
    }

    k_post<<<gR, 256, 0, stream>>>(cam, rays, acc, nsdf, unfin, listS, cnt + 21,
                                   smin, smax, out, R);

    // chunked sampler with exact first-negative early exit
    chunk(listS, cnt + 21, 0, 25, 1);                      // samples 0..24 + 99
    k_scan<<<gR, 256, 0, stream>>>(sdfv, listS, cnt + 21, 0, 25, 0,
                                   listC1, cnt + 22, nEval);
    chunk(listC1, cnt + 22, 25, 25, 0);                    // samples 25..49
    k_scan<<<gR, 256, 0, stream>>>(sdfv, listC1, cnt + 22, 25, 25, 0,
                                   listC2, cnt + 23, nEval);
    chunk(listC2, cnt + 23, 50, 25, 0);                    // samples 50..74
    k_scan<<<gR, 256, 0, stream>>>(sdfv, listC2, cnt + 23, 50, 25, 100,
                                   listC3, cnt + 24, nEval);
    chunk(listC3, cnt + 24, 75, 24, 0);                    // samples 75..98

    hipLaunchKernelGGL(k_secfin, dim3(gSec), dim3(256), 0, stream,
                       cam, rays, R, listS, cnt + 21, sdfv, nEval, smin, smax, out,
                       W1, b1, W2, b2, W3, b3);
}